// Round 20
// baseline (767.004 us; speedup 1.0000x reference)
//
#include <hip/hip_runtime.h>

#define NN 50000
#define NE 800000
#define NOUT (NN * 128)
#define PF_TOTAL 100608

typedef unsigned int u32;
typedef unsigned short u16;

__device__ __forceinline__ float bf2f(u16 u) { return __uint_as_float(((u32)u) << 16); }
__device__ __forceinline__ u32 f2bf_u(float f) {
  u32 u = __float_as_uint(f);
  u += 0x7FFFu + ((u >> 16) & 1u);
  return u >> 16;
}
__device__ __forceinline__ u32 pk2(float a, float b) {
  return f2bf_u(a) | (f2bf_u(b) << 16);
}
__device__ __forceinline__ float lo_f(u32 v) { return __uint_as_float(v << 16); }
__device__ __forceinline__ float hi_f(u32 v) { return __uint_as_float(v & 0xFFFF0000u); }
__device__ __forceinline__ float h2f(u16 h) {
  u32 sg = ((u32)h >> 15) & 1u, e = ((u32)h >> 10) & 0x1Fu, mm = (u32)h & 0x3FFu;
  u32 o;
  if (e == 0u) o = sg << 31;
  else if (e == 31u) o = (sg << 31) | 0x7F800000u | (mm << 13);
  else o = (sg << 31) | ((e + 112u) << 23) | (mm << 13);
  return __uint_as_float(o);
}
__device__ __forceinline__ float lrelu(float x) { return x > 0.f ? x : 0.2f * x; }
__device__ __forceinline__ u32 umin32(u32 a, u32 b) { return a < b ? a : b; }

// fmode: 0=bf16, 1=fp32 (measured reality), 2=fp16
__device__ __forceinline__ float cvt_one(const void* p, int j, u32 fmode) {
  if (fmode == 1u) return ((const float*)p)[j];
  if (fmode == 2u) return h2f(((const u16*)p)[j]);
  return bf2f(((const u16*)p)[j]);
}

// identifier-named kernel retained (unused)
__global__ __launch_bounds__(256) void MultiScaleGNN_54769422958784_kernel(
    float* out, float val, int n) {
  int i = blockIdx.x * 256 + threadIdx.x;
  if (i < n) out[i] = val;
}

__global__ __launch_bounds__(64) void detect_kernel(const u32* lng, const int* ei,
                                                    u32* flag) {
  if (threadIdx.x == 0) {
    u32 v0 = lng[0], v1 = lng[1];
    u32 fm;
    if (v0 == 0x3F803F80u && v1 == 0x3F803F80u) fm = 0u;
    else if (v0 == 0x3F800000u && v1 == 0x3F800000u) fm = 1u;
    else if (v0 == 0x3C003C00u && v1 == 0x3C003C00u) fm = 2u;
    else fm = 1u;
    flag[0] = fm;
    flag[1] = ((ei[1] | ei[3] | ei[5] | ei[7]) == 0) ? 1u : 0u;
  }
}

__global__ __launch_bounds__(256) void cvt_x_kernel(const void* in, float* out, int n,
                                                    const u32* flag) {
  u32 fm = flag[0];
  int i = blockIdx.x * 256 + threadIdx.x;
  if (i < n) out[i] = cvt_one(in, i, fm);
}

__global__ __launch_bounds__(256) void cvt_params_kernel(const void* g0, const void* g1,
                                                         const void* g2, const void* g3,
                                                         const void* g4, const void* g5,
                                                         const void* g6, const void* g7,
                                                         float* out, const u32* flag) {
  u32 fm = flag[0];
  int i = blockIdx.x * 256 + threadIdx.x;
  if (i >= PF_TOTAL) return;
  int offs[9] = {0, 49152, 49536, 98688, 99072, 99456, 99840, 100224, 100608};
  const void* ptrs[8] = {g0, g1, g2, g3, g4, g5, g6, g7};
  int r = 0;
  while (i >= offs[r + 1]) r++;
  out[i] = cvt_one(ptrs[r], i - offs[r], fm);
}

__global__ __launch_bounds__(256) void zero2_kernel(u32* a, u32* b, int n) {
  int i = blockIdx.x * 256 + threadIdx.x;
  if (i < n) {
    a[i] = 0u;
    b[i] = 0u;
  }
}

__global__ __launch_bounds__(256) void hist_kernel(const int* ei, u32* cnt, int e, int n,
                                                   const u32* flag) {
  int i = blockIdx.x * blockDim.x + threadIdx.x;
  if (i >= e) return;
  int d = flag[1] ? ei[2 * e + 2 * i] : ei[e + i];
  if ((u32)d < (u32)n) atomicAdd(&cnt[d], 1u);
}

__global__ __launch_bounds__(1024) void scan_kernel(const u32* counts, u32* rowptr,
                                                    float* dinv, int n) {
  __shared__ u32 wsum[16];
  __shared__ u32 carry_sh;
  int tid = threadIdx.x, lane = tid & 63, wid = tid >> 6;
  if (tid == 0) carry_sh = 0u;
  __syncthreads();
  for (int base = 0; base < n; base += 4096) {
    int i0 = base + tid * 4;
    u32 c0 = (i0 + 0 < n) ? counts[i0 + 0] : 0u;
    u32 c1 = (i0 + 1 < n) ? counts[i0 + 1] : 0u;
    u32 c2 = (i0 + 2 < n) ? counts[i0 + 2] : 0u;
    u32 c3 = (i0 + 3 < n) ? counts[i0 + 3] : 0u;
    u32 tsum = c0 + c1 + c2 + c3;
    u32 v = tsum;
#pragma unroll
    for (int off = 1; off < 64; off <<= 1) {
      u32 t = (u32)__shfl_up((int)v, off);
      if (lane >= off) v += t;
    }
    if (lane == 63) wsum[wid] = v;
    __syncthreads();
    if (wid == 0 && lane < 16) {
      u32 w = wsum[lane];
#pragma unroll
      for (int off = 1; off < 16; off <<= 1) {
        u32 t = (u32)__shfl_up((int)w, off);
        if (lane >= off) w += t;
      }
      wsum[lane] = w;
    }
    __syncthreads();
    u32 excl = v - tsum + ((wid > 0) ? wsum[wid - 1] : 0u) + carry_sh;
    if (i0 + 0 < n) { rowptr[i0 + 0] = excl; dinv[i0 + 0] = rsqrtf((float)(c0 + 1u)); }
    excl += c0;
    if (i0 + 1 < n) { rowptr[i0 + 1] = excl; dinv[i0 + 1] = rsqrtf((float)(c1 + 1u)); }
    excl += c1;
    if (i0 + 2 < n) { rowptr[i0 + 2] = excl; dinv[i0 + 2] = rsqrtf((float)(c2 + 1u)); }
    excl += c2;
    if (i0 + 3 < n) { rowptr[i0 + 3] = excl; dinv[i0 + 3] = rsqrtf((float)(c3 + 1u)); }
    excl += c3;
    __syncthreads();
    if (tid == 1023) carry_sh = excl;
    __syncthreads();
  }
  if (threadIdx.x == 0) rowptr[n] = carry_sh;
}

__global__ __launch_bounds__(256) void scatter_kernel(const int* ei, const u32* rowptr,
                                                      u32* fill, int* col, int e, int n,
                                                      const u32* flag) {
  int i = blockIdx.x * blockDim.x + threadIdx.x;
  if (i >= e) return;
  u32 em = flag[1];
  int s = em ? ei[2 * i] : ei[i];
  int d = em ? ei[2 * e + 2 * i] : ei[e + i];
  if ((u32)d >= (u32)n) return;
  u32 p = rowptr[d] + atomicAdd(&fill[d], 1u);
  if (p < (u32)e) col[p] = ((u32)s < (u32)n) ? s : 0;
}

// GEMM: [M,128] fp32 @ [128,128] fp32 -> O fp32 [M,128] and Oh packed-bf16 [M,64]u32.
__global__ __launch_bounds__(256) void gemm_kernel(const float* A, const float* W,
                                                   float* O, u32* __restrict__ Oh,
                                                   const float* dinv, int M) {
  __shared__ float As[16][132];
  __shared__ float Bs[16][128];
  int tid = threadIdx.x;
  int row0 = blockIdx.x * 128;
  int tx = tid & 15, ty = tid >> 4;
  int c0 = tx * 8, r0 = ty * 8;
  float acc[8][8];
  for (int i = 0; i < 8; i++)
    for (int j = 0; j < 8; j++) acc[i][j] = 0.f;
  for (int k0 = 0; k0 < 128; k0 += 16) {
    for (int it = 0; it < 2; it++) {
      int r = (tid >> 2) + it * 64;
      int kq = (tid & 3) * 4;
      float4 av = make_float4(0.f, 0.f, 0.f, 0.f);
      if (row0 + r < M) av = *(const float4*)(A + (size_t)(row0 + r) * 128 + k0 + kq);
      As[kq + 0][r] = av.x;
      As[kq + 1][r] = av.y;
      As[kq + 2][r] = av.z;
      As[kq + 3][r] = av.w;
    }
    {
      int k = tid >> 4;
      int c8 = (tid & 15) * 8;
      float4 w0 = *(const float4*)(W + (k0 + k) * 128 + c8);
      float4 w1 = *(const float4*)(W + (k0 + k) * 128 + c8 + 4);
      *(float4*)&Bs[k][c8] = w0;
      *(float4*)&Bs[k][c8 + 4] = w1;
    }
    __syncthreads();
#pragma unroll
    for (int kk = 0; kk < 16; kk++) {
      float a[8], b[8];
#pragma unroll
      for (int i = 0; i < 8; i++) a[i] = As[kk][r0 + i];
#pragma unroll
      for (int j = 0; j < 8; j++) b[j] = Bs[kk][c0 + j];
#pragma unroll
      for (int i = 0; i < 8; i++)
#pragma unroll
        for (int j = 0; j < 8; j++) acc[i][j] = fmaf(a[i], b[j], acc[i][j]);
    }
    __syncthreads();
  }
  for (int i = 0; i < 8; i++) {
    int r = row0 + r0 + i;
    if (r < M) {
      float sc = (dinv != 0) ? dinv[r] : 1.0f;
      float v0 = acc[i][0] * sc, v1 = acc[i][1] * sc, v2 = acc[i][2] * sc,
            v3 = acc[i][3] * sc;
      float v4 = acc[i][4] * sc, v5 = acc[i][5] * sc, v6 = acc[i][6] * sc,
            v7 = acc[i][7] * sc;
      *(float4*)(O + (size_t)r * 128 + c0) = make_float4(v0, v1, v2, v3);
      *(float4*)(O + (size_t)r * 128 + c0 + 4) = make_float4(v4, v5, v6, v7);
      uint4 p = make_uint4(pk2(v0, v1), pk2(v2, v3), pk2(v4, v5), pk2(v6, v7));
      *(uint4*)(Oh + (size_t)r * 64 + tx * 4) = p;
    }
  }
}

// GCN aggregation: paired-edge uint2 bf16 gathers, fp32 accumulate.
__global__ __launch_bounds__(256) void gcn_agg_kernel(const float* xws,
                                                      const u32* __restrict__ xh,
                                                      const int* col, const u32* rowptr,
                                                      const float* dinv, const float* bias,
                                                      float* out, int n) {
  __shared__ int lds_s[4][64];
  int wslot = threadIdx.x >> 6;
  int lane = threadIdx.x & 63;
  int half = lane >> 5;
  int l32 = lane & 31;
  int d = blockIdx.x * 4 + wslot;
  if (d >= n) return;
  u32 start = umin32(rowptr[d], (u32)NE), end = umin32(rowptr[d + 1], (u32)NE);
  float4 acc = make_float4(0.f, 0.f, 0.f, 0.f);
  for (u32 base = start; base < end; base += 64) {
    u32 i = base + lane;
    int cnt = (int)umin32(64u, end - base);
    if (i < end) lds_s[wslot][lane] = col[i];
#pragma unroll 4
    for (int j = 0; j < cnt; j += 2) {
      int jj = j + half;
      bool ok = jj < cnt;
      int s = lds_s[wslot][ok ? jj : j];
      uint2 v = *(const uint2*)(xh + (size_t)s * 64 + l32 * 2);
      if (ok) {
        acc.x += lo_f(v.x);
        acc.y += hi_f(v.x);
        acc.z += lo_f(v.y);
        acc.w += hi_f(v.y);
      }
    }
  }
  acc.x += __shfl_xor(acc.x, 32);
  acc.y += __shfl_xor(acc.y, 32);
  acc.z += __shfl_xor(acc.z, 32);
  acc.w += __shfl_xor(acc.w, 32);
  if (half == 0) {
    int c0 = l32 * 4;
    float4 vs = *(const float4*)(xws + (size_t)d * 128 + c0);
    float dd = dinv[d];
    float4 o;
    o.x = dd * (acc.x + vs.x) + bias[c0];
    o.y = dd * (acc.y + vs.y) + bias[c0 + 1];
    o.z = dd * (acc.z + vs.z) + bias[c0 + 2];
    o.w = dd * (acc.w + vs.w) + bias[c0 + 3];
    *(float4*)(out + (size_t)d * 128 + c0) = o;
  }
}

// attention logits a_src/a_dst [n,4]
__global__ __launch_bounds__(256) void att_kernel(const float* xw2, const float* att_src,
                                                  const float* att_dst, float* a_src,
                                                  float* a_dst, int n) {
  int gid = blockIdx.x * 256 + threadIdx.x;
  int node = gid >> 7;
  int c = gid & 127;
  if (node >= n) return;
  float v = xw2[(size_t)node * 128 + c];
  float ps = v * att_src[c];
  float pd = v * att_dst[c];
#pragma unroll
  for (int off = 16; off; off >>= 1) {
    ps += __shfl_xor(ps, off);
    pd += __shfl_xor(pd, off);
  }
  if ((threadIdx.x & 31) == 0) {
    int h = c >> 5;
    a_src[node * 4 + h] = ps;
    a_dst[node * 4 + h] = pd;
  }
}

// GAT aggregation + residual + LayerNorm + ReLU. One wave per node.
// SINGLE-PASS online softmax; LDS ee layout [64][4] (conflict-free reads);
// paired-edge uint2 bf16 gathers.
__global__ __launch_bounds__(256) void gat_agg_kernel(
    const float* xw2, const u32* __restrict__ xh, const float* a_src4,
    const float* a_dst4, const int* col, const u32* rowptr, const float* hgcn,
    const float* gat_b, const float* ln_g, const float* ln_b, float* __restrict__ out,
    int n) {
  __shared__ u32 lds_s[4][64];
  __shared__ float lds_ee[4][64][4];
  int wslot = threadIdx.x >> 6;
  int lane = threadIdx.x & 63;
  int half = lane >> 5;
  int l32 = lane & 31;
  int head4 = l32 >> 3;  // 4 channels/lane, 32 channels/head
  int d = blockIdx.x * 4 + wslot;
  if (d >= n) return;
  u32 start = umin32(rowptr[d], (u32)NE), end = umin32(rowptr[d + 1], (u32)NE);
  float4 ad = *(const float4*)(a_dst4 + (size_t)d * 4);
  float4 asl = *(const float4*)(a_src4 + (size_t)d * 4);
  float4 es;
  es.x = lrelu(asl.x + ad.x);
  es.y = lrelu(asl.y + ad.y);
  es.z = lrelu(asl.z + ad.z);
  es.w = lrelu(asl.w + ad.w);
  float4 m = es;  // running max (self logit included from the start)
  float4 zp = make_float4(0.f, 0.f, 0.f, 0.f);
  float4 acc = make_float4(0.f, 0.f, 0.f, 0.f);
  for (u32 base = start; base < end; base += 64) {
    u32 i = base + lane;
    int cnt = (int)umin32(64u, end - base);
    bool act = i < end;
    float4 l = make_float4(-1e30f, -1e30f, -1e30f, -1e30f);
    int s = 0;
    if (act) {
      s = col[i];
      float4 a = *(const float4*)(a_src4 + (size_t)s * 4);
      l.x = lrelu(a.x + ad.x);
      l.y = lrelu(a.y + ad.y);
      l.z = lrelu(a.z + ad.z);
      l.w = lrelu(a.w + ad.w);
    }
    // chunk max across wave, merge into running max, rescale state
    float4 cm = l;
#pragma unroll
    for (int off = 32; off; off >>= 1) {
      cm.x = fmaxf(cm.x, __shfl_xor(cm.x, off));
      cm.y = fmaxf(cm.y, __shfl_xor(cm.y, off));
      cm.z = fmaxf(cm.z, __shfl_xor(cm.z, off));
      cm.w = fmaxf(cm.w, __shfl_xor(cm.w, off));
    }
    float4 mn;
    mn.x = fmaxf(m.x, cm.x);
    mn.y = fmaxf(m.y, cm.y);
    mn.z = fmaxf(m.z, cm.z);
    mn.w = fmaxf(m.w, cm.w);
    float4 f;
    f.x = __expf(m.x - mn.x);
    f.y = __expf(m.y - mn.y);
    f.z = __expf(m.z - mn.z);
    f.w = __expf(m.w - mn.w);
    m = mn;
    zp.x *= f.x;
    zp.y *= f.y;
    zp.z *= f.z;
    zp.w *= f.w;
    float fsel = (head4 == 0) ? f.x : (head4 == 1) ? f.y : (head4 == 2) ? f.z : f.w;
    acc.x *= fsel;
    acc.y *= fsel;
    acc.z *= fsel;
    acc.w *= fsel;
    if (act) {
      float ex = __expf(l.x - m.x);
      float ey = __expf(l.y - m.y);
      float ez = __expf(l.z - m.z);
      float ew = __expf(l.w - m.w);
      zp.x += ex;
      zp.y += ey;
      zp.z += ez;
      zp.w += ew;
      lds_s[wslot][lane] = (u32)s;
      *(float4*)&lds_ee[wslot][lane][0] = make_float4(ex, ey, ez, ew);
    }
#pragma unroll 4
    for (int j = 0; j < cnt; j += 2) {
      int jj = j + half;
      bool ok = jj < cnt;
      int idx = ok ? jj : j;
      u32 sg = lds_s[wslot][idx];
      float w = lds_ee[wslot][idx][head4];
      uint2 v = *(const uint2*)(xh + (size_t)sg * 64 + l32 * 2);
      if (ok) {
        acc.x = fmaf(w, lo_f(v.x), acc.x);
        acc.y = fmaf(w, hi_f(v.x), acc.y);
        acc.z = fmaf(w, lo_f(v.y), acc.z);
        acc.w = fmaf(w, hi_f(v.y), acc.w);
      }
    }
  }
  // combine paired halves
  acc.x += __shfl_xor(acc.x, 32);
  acc.y += __shfl_xor(acc.y, 32);
  acc.z += __shfl_xor(acc.z, 32);
  acc.w += __shfl_xor(acc.w, 32);
  // softmax denominator (+ self edge)
  float4 ees;
  ees.x = __expf(es.x - m.x);
  ees.y = __expf(es.y - m.y);
  ees.z = __expf(es.z - m.z);
  ees.w = __expf(es.w - m.w);
#pragma unroll
  for (int off = 32; off; off >>= 1) {
    zp.x += __shfl_xor(zp.x, off);
    zp.y += __shfl_xor(zp.y, off);
    zp.z += __shfl_xor(zp.z, off);
    zp.w += __shfl_xor(zp.w, off);
  }
  zp.x += ees.x;
  zp.y += ees.y;
  zp.z += ees.z;
  zp.w += ees.w;
  float wsel = (head4 == 0) ? ees.x : (head4 == 1) ? ees.y : (head4 == 2) ? ees.z : ees.w;
  float zsel = (head4 == 0) ? zp.x : (head4 == 1) ? zp.y : (head4 == 2) ? zp.z : zp.w;
  int c0 = l32 * 4;
  float4 vs = *(const float4*)(xw2 + (size_t)d * 128 + c0);
  acc.x = fmaf(wsel, vs.x, acc.x);
  acc.y = fmaf(wsel, vs.y, acc.y);
  acc.z = fmaf(wsel, vs.z, acc.z);
  acc.w = fmaf(wsel, vs.w, acc.w);
  float rz = 1.0f / zsel;
  float4 hg = *(const float4*)(hgcn + (size_t)d * 128 + c0);
  float t0 = acc.x * rz + gat_b[c0] + hg.x;
  float t1 = acc.y * rz + gat_b[c0 + 1] + hg.y;
  float t2 = acc.z * rz + gat_b[c0 + 2] + hg.z;
  float t3 = acc.w * rz + gat_b[c0 + 3] + hg.w;
  // LayerNorm over 128 channels; halves hold duplicate values -> divide by 256
  float ssum = t0 + t1 + t2 + t3;
#pragma unroll
  for (int off = 32; off; off >>= 1) ssum += __shfl_xor(ssum, off);
  float mu = ssum * (1.0f / 256.0f);
  float d0 = t0 - mu, d1 = t1 - mu, d2 = t2 - mu, d3 = t3 - mu;
  float vv = d0 * d0 + d1 * d1 + d2 * d2 + d3 * d3;
#pragma unroll
  for (int off = 32; off; off >>= 1) vv += __shfl_xor(vv, off);
  float rstd = rsqrtf(vv * (1.0f / 256.0f) + 1e-5f);
  if (half == 0) {
    float4 o;
    o.x = fmaxf(fmaf(d0 * rstd, ln_g[c0], ln_b[c0]), 0.f);
    o.y = fmaxf(fmaf(d1 * rstd, ln_g[c0 + 1], ln_b[c0 + 1]), 0.f);
    o.z = fmaxf(fmaf(d2 * rstd, ln_g[c0 + 2], ln_b[c0 + 2]), 0.f);
    o.w = fmaxf(fmaf(d3 * rstd, ln_g[c0 + 3], ln_b[c0 + 3]), 0.f);
    *(float4*)(out + (size_t)d * 128 + c0) = o;
  }
}

extern "C" void kernel_launch(void* const* d_in, const int* in_sizes, int n_in,
                              void* d_out, int out_size, void* d_ws, size_t ws_size,
                              hipStream_t stream) {
  const int N = NN, E = NE;
  (void)in_sizes;
  (void)n_in;
  (void)out_size;
  (void)ws_size;

  // ---- workspace layout ----
  char* ws = (char*)d_ws;
  size_t off = 0;
  float* xw = (float*)(ws + off);   off += (size_t)N * 128 * 4;
  u32* xwh = (u32*)(ws + off);      off += (size_t)N * 64 * 4;
  float* hgcn = (float*)(ws + off); off += (size_t)N * 128 * 4;
  float* hbuf = (float*)(ws + off); off += (size_t)N * 128 * 4;
  float* asrc = (float*)(ws + off); off += (size_t)N * 4 * 4;
  float* adst = (float*)(ws + off); off += (size_t)N * 4 * 4;
  float* dinv = (float*)(ws + off); off += (size_t)N * 4;
  u32* counts = (u32*)(ws + off);   off += (size_t)N * 4;
  u32* fillc = (u32*)(ws + off);    off += (size_t)N * 4;
  u32* rowptr = (u32*)(ws + off);   off += (size_t)(N + 1) * 4 + 252;
  int* col = (int*)(ws + off);      off += (size_t)E * 4;
  float* pf = (float*)(ws + off);   off += (size_t)PF_TOTAL * 4;
  u32* flag = (u32*)(ws + off);     off += 256;

  // ---- input conversion + CSR build ----
  const int* edge_index = (const int*)d_in[1];
  detect_kernel<<<1, 64, 0, stream>>>((const u32*)d_in[8], edge_index, flag);
  cvt_params_kernel<<<(PF_TOTAL + 255) / 256, 256, 0, stream>>>(
      d_in[2], d_in[3], d_in[4], d_in[5], d_in[6], d_in[7], d_in[8], d_in[9], pf, flag);
  cvt_x_kernel<<<(N * 128 + 255) / 256, 256, 0, stream>>>(d_in[0], hbuf, N * 128, flag);
  zero2_kernel<<<(N + 255) / 256, 256, 0, stream>>>(counts, fillc, N);
  hist_kernel<<<(E + 255) / 256, 256, 0, stream>>>(edge_index, counts, E, N, flag);
  scan_kernel<<<1, 1024, 0, stream>>>(counts, rowptr, dinv, N);
  scatter_kernel<<<(E + 255) / 256, 256, 0, stream>>>(edge_index, rowptr, fillc, col, E, N,
                                                      flag);

  const float* gcn_w = pf + 0;
  const float* gcn_b = pf + 49152;
  const float* gat_w = pf + 49536;
  const float* att_s = pf + 98688;
  const float* att_d = pf + 99072;
  const float* gat_b = pf + 99456;
  const float* ln_g = pf + 99840;
  const float* ln_b = pf + 100224;

  // ---- 3 layers ----
  int gblocks = (N + 127) / 128;
  int ablocks = (N + 3) / 4;
  for (int l = 0; l < 3; l++) {
    gemm_kernel<<<gblocks, 256, 0, stream>>>(hbuf, gcn_w + (size_t)l * 16384, xw, xwh,
                                             dinv, N);
    gcn_agg_kernel<<<ablocks, 256, 0, stream>>>(xw, xwh, col, rowptr, dinv,
                                                gcn_b + l * 128, hgcn, N);
    gemm_kernel<<<gblocks, 256, 0, stream>>>(hgcn, gat_w + (size_t)l * 16384, xw, xwh,
                                             (const float*)0, N);
    att_kernel<<<(N * 128) / 256, 256, 0, stream>>>(xw, att_s + l * 128, att_d + l * 128,
                                                    asrc, adst, N);
    float* dst = (l < 2) ? hbuf : (float*)d_out;
    gat_agg_kernel<<<ablocks, 256, 0, stream>>>(xw, xwh, asrc, adst, col, rowptr, hgcn,
                                                gat_b + l * 128, ln_g + l * 128,
                                                ln_b + l * 128, dst, N);
  }
}

// Round 21
// 730.025 us; speedup vs baseline: 1.0507x; 1.0507x over previous
//
#include <hip/hip_runtime.h>

#define NN 50000
#define NE 800000
#define NOUT (NN * 128)
#define PF_TOTAL 100608

typedef unsigned int u32;
typedef unsigned short u16;

__device__ __forceinline__ float bf2f(u16 u) { return __uint_as_float(((u32)u) << 16); }
__device__ __forceinline__ u32 f2bf_u(float f) {
  u32 u = __float_as_uint(f);
  u += 0x7FFFu + ((u >> 16) & 1u);
  return u >> 16;
}
__device__ __forceinline__ u32 pk2(float a, float b) {
  return f2bf_u(a) | (f2bf_u(b) << 16);
}
__device__ __forceinline__ float lo_f(u32 v) { return __uint_as_float(v << 16); }
__device__ __forceinline__ float hi_f(u32 v) { return __uint_as_float(v & 0xFFFF0000u); }
__device__ __forceinline__ float h2f(u16 h) {
  u32 sg = ((u32)h >> 15) & 1u, e = ((u32)h >> 10) & 0x1Fu, mm = (u32)h & 0x3FFu;
  u32 o;
  if (e == 0u) o = sg << 31;
  else if (e == 31u) o = (sg << 31) | 0x7F800000u | (mm << 13);
  else o = (sg << 31) | ((e + 112u) << 23) | (mm << 13);
  return __uint_as_float(o);
}
__device__ __forceinline__ float lrelu(float x) { return x > 0.f ? x : 0.2f * x; }
__device__ __forceinline__ u32 umin32(u32 a, u32 b) { return a < b ? a : b; }

// fmode: 0=bf16, 1=fp32 (measured reality), 2=fp16
__device__ __forceinline__ float cvt_one(const void* p, int j, u32 fmode) {
  if (fmode == 1u) return ((const float*)p)[j];
  if (fmode == 2u) return h2f(((const u16*)p)[j]);
  return bf2f(((const u16*)p)[j]);
}

// identifier-named kernel retained (unused)
__global__ __launch_bounds__(256) void MultiScaleGNN_54769422958784_kernel(
    float* out, float val, int n) {
  int i = blockIdx.x * 256 + threadIdx.x;
  if (i < n) out[i] = val;
}

__global__ __launch_bounds__(64) void detect_kernel(const u32* lng, const int* ei,
                                                    u32* flag) {
  if (threadIdx.x == 0) {
    u32 v0 = lng[0], v1 = lng[1];
    u32 fm;
    if (v0 == 0x3F803F80u && v1 == 0x3F803F80u) fm = 0u;
    else if (v0 == 0x3F800000u && v1 == 0x3F800000u) fm = 1u;
    else if (v0 == 0x3C003C00u && v1 == 0x3C003C00u) fm = 2u;
    else fm = 1u;
    flag[0] = fm;
    flag[1] = ((ei[1] | ei[3] | ei[5] | ei[7]) == 0) ? 1u : 0u;
  }
}

__global__ __launch_bounds__(256) void cvt_x_kernel(const void* in, float* out, int n,
                                                    const u32* flag) {
  u32 fm = flag[0];
  int i = blockIdx.x * 256 + threadIdx.x;
  if (i < n) out[i] = cvt_one(in, i, fm);
}

__global__ __launch_bounds__(256) void cvt_params_kernel(const void* g0, const void* g1,
                                                         const void* g2, const void* g3,
                                                         const void* g4, const void* g5,
                                                         const void* g6, const void* g7,
                                                         float* out, const u32* flag) {
  u32 fm = flag[0];
  int i = blockIdx.x * 256 + threadIdx.x;
  if (i >= PF_TOTAL) return;
  int offs[9] = {0, 49152, 49536, 98688, 99072, 99456, 99840, 100224, 100608};
  const void* ptrs[8] = {g0, g1, g2, g3, g4, g5, g6, g7};
  int r = 0;
  while (i >= offs[r + 1]) r++;
  out[i] = cvt_one(ptrs[r], i - offs[r], fm);
}

__global__ __launch_bounds__(256) void zero2_kernel(u32* a, u32* b, int n) {
  int i = blockIdx.x * 256 + threadIdx.x;
  if (i < n) {
    a[i] = 0u;
    b[i] = 0u;
  }
}

__global__ __launch_bounds__(256) void hist_kernel(const int* ei, u32* cnt, int e, int n,
                                                   const u32* flag) {
  int i = blockIdx.x * blockDim.x + threadIdx.x;
  if (i >= e) return;
  int d = flag[1] ? ei[2 * e + 2 * i] : ei[e + i];
  if ((u32)d < (u32)n) atomicAdd(&cnt[d], 1u);
}

__global__ __launch_bounds__(1024) void scan_kernel(const u32* counts, u32* rowptr,
                                                    float* dinv, int n) {
  __shared__ u32 wsum[16];
  __shared__ u32 carry_sh;
  int tid = threadIdx.x, lane = tid & 63, wid = tid >> 6;
  if (tid == 0) carry_sh = 0u;
  __syncthreads();
  for (int base = 0; base < n; base += 4096) {
    int i0 = base + tid * 4;
    u32 c0 = (i0 + 0 < n) ? counts[i0 + 0] : 0u;
    u32 c1 = (i0 + 1 < n) ? counts[i0 + 1] : 0u;
    u32 c2 = (i0 + 2 < n) ? counts[i0 + 2] : 0u;
    u32 c3 = (i0 + 3 < n) ? counts[i0 + 3] : 0u;
    u32 tsum = c0 + c1 + c2 + c3;
    u32 v = tsum;
#pragma unroll
    for (int off = 1; off < 64; off <<= 1) {
      u32 t = (u32)__shfl_up((int)v, off);
      if (lane >= off) v += t;
    }
    if (lane == 63) wsum[wid] = v;
    __syncthreads();
    if (wid == 0 && lane < 16) {
      u32 w = wsum[lane];
#pragma unroll
      for (int off = 1; off < 16; off <<= 1) {
        u32 t = (u32)__shfl_up((int)w, off);
        if (lane >= off) w += t;
      }
      wsum[lane] = w;
    }
    __syncthreads();
    u32 excl = v - tsum + ((wid > 0) ? wsum[wid - 1] : 0u) + carry_sh;
    if (i0 + 0 < n) { rowptr[i0 + 0] = excl; dinv[i0 + 0] = rsqrtf((float)(c0 + 1u)); }
    excl += c0;
    if (i0 + 1 < n) { rowptr[i0 + 1] = excl; dinv[i0 + 1] = rsqrtf((float)(c1 + 1u)); }
    excl += c1;
    if (i0 + 2 < n) { rowptr[i0 + 2] = excl; dinv[i0 + 2] = rsqrtf((float)(c2 + 1u)); }
    excl += c2;
    if (i0 + 3 < n) { rowptr[i0 + 3] = excl; dinv[i0 + 3] = rsqrtf((float)(c3 + 1u)); }
    excl += c3;
    __syncthreads();
    if (tid == 1023) carry_sh = excl;
    __syncthreads();
  }
  if (threadIdx.x == 0) rowptr[n] = carry_sh;
}

__global__ __launch_bounds__(256) void scatter_kernel(const int* ei, const u32* rowptr,
                                                      u32* fill, int* col, int e, int n,
                                                      const u32* flag) {
  int i = blockIdx.x * blockDim.x + threadIdx.x;
  if (i >= e) return;
  u32 em = flag[1];
  int s = em ? ei[2 * i] : ei[i];
  int d = em ? ei[2 * e + 2 * i] : ei[e + i];
  if ((u32)d >= (u32)n) return;
  u32 p = rowptr[d] + atomicAdd(&fill[d], 1u);
  if (p < (u32)e) col[p] = ((u32)s < (u32)n) ? s : 0;
}

// GEMM: [M,128] fp32 @ [128,128] fp32 -> Oh packed-bf16 [M,64]u32 only.
// dinv!=null: row-scale (GCN). att_s!=null: fused attention logits ->
// asrc/adst [M,4] (per-head dots of output row with att_s/att_d).
__global__ __launch_bounds__(256) void gemm_kernel(const float* A, const float* W,
                                                   u32* __restrict__ Oh, const float* dinv,
                                                   const float* att_s, const float* att_d,
                                                   float* asrc, float* adst, int M) {
  __shared__ float As[16][132];
  __shared__ float Bs[16][128];
  int tid = threadIdx.x;
  int row0 = blockIdx.x * 128;
  int tx = tid & 15, ty = tid >> 4;
  int c0 = tx * 8, r0 = ty * 8;
  float acc[8][8];
  for (int i = 0; i < 8; i++)
    for (int j = 0; j < 8; j++) acc[i][j] = 0.f;
  for (int k0 = 0; k0 < 128; k0 += 16) {
    for (int it = 0; it < 2; it++) {
      int r = (tid >> 2) + it * 64;
      int kq = (tid & 3) * 4;
      float4 av = make_float4(0.f, 0.f, 0.f, 0.f);
      if (row0 + r < M) av = *(const float4*)(A + (size_t)(row0 + r) * 128 + k0 + kq);
      As[kq + 0][r] = av.x;
      As[kq + 1][r] = av.y;
      As[kq + 2][r] = av.z;
      As[kq + 3][r] = av.w;
    }
    {
      int k = tid >> 4;
      int c8 = (tid & 15) * 8;
      float4 w0 = *(const float4*)(W + (k0 + k) * 128 + c8);
      float4 w1 = *(const float4*)(W + (k0 + k) * 128 + c8 + 4);
      *(float4*)&Bs[k][c8] = w0;
      *(float4*)&Bs[k][c8 + 4] = w1;
    }
    __syncthreads();
#pragma unroll
    for (int kk = 0; kk < 16; kk++) {
      float a[8], b[8];
#pragma unroll
      for (int i = 0; i < 8; i++) a[i] = As[kk][r0 + i];
#pragma unroll
      for (int j = 0; j < 8; j++) b[j] = Bs[kk][c0 + j];
#pragma unroll
      for (int i = 0; i < 8; i++)
#pragma unroll
        for (int j = 0; j < 8; j++) acc[i][j] = fmaf(a[i], b[j], acc[i][j]);
    }
    __syncthreads();
  }
  // attention weights for this thread's 8 columns (all within head tx>>2)
  float ws_[8], wd_[8];
  if (att_s) {
#pragma unroll
    for (int j = 0; j < 8; j++) {
      ws_[j] = att_s[c0 + j];
      wd_[j] = att_d[c0 + j];
    }
  }
  int head = tx >> 2;
  for (int i = 0; i < 8; i++) {
    int r = row0 + r0 + i;
    if (r < M) {
      float sc = (dinv != 0) ? dinv[r] : 1.0f;
      float v0 = acc[i][0] * sc, v1 = acc[i][1] * sc, v2 = acc[i][2] * sc,
            v3 = acc[i][3] * sc;
      float v4 = acc[i][4] * sc, v5 = acc[i][5] * sc, v6 = acc[i][6] * sc,
            v7 = acc[i][7] * sc;
      uint4 p = make_uint4(pk2(v0, v1), pk2(v2, v3), pk2(v4, v5), pk2(v6, v7));
      *(uint4*)(Oh + (size_t)r * 64 + tx * 4) = p;
      if (att_s) {
        float ps = v0 * ws_[0] + v1 * ws_[1] + v2 * ws_[2] + v3 * ws_[3] + v4 * ws_[4] +
                   v5 * ws_[5] + v6 * ws_[6] + v7 * ws_[7];
        float pd = v0 * wd_[0] + v1 * wd_[1] + v2 * wd_[2] + v3 * wd_[3] + v4 * wd_[4] +
                   v5 * wd_[5] + v6 * wd_[6] + v7 * wd_[7];
        // reduce across the 4 tx sharing this head (lane bits 0-1 = tx bits 0-1)
        ps += __shfl_xor(ps, 1);
        ps += __shfl_xor(ps, 2);
        pd += __shfl_xor(pd, 1);
        pd += __shfl_xor(pd, 2);
        if ((tx & 3) == 0) {
          asrc[(size_t)r * 4 + head] = ps;
          adst[(size_t)r * 4 + head] = pd;
        }
      }
    }
  }
}

// GCN aggregation: paired-edge uint2 bf16 gathers; self term also from bf16.
__global__ __launch_bounds__(256) void gcn_agg_kernel(const u32* __restrict__ xh,
                                                      const int* col, const u32* rowptr,
                                                      const float* dinv, const float* bias,
                                                      float* out, int n) {
  __shared__ int lds_s[4][64];
  int wslot = threadIdx.x >> 6;
  int lane = threadIdx.x & 63;
  int half = lane >> 5;
  int l32 = lane & 31;
  int d = blockIdx.x * 4 + wslot;
  if (d >= n) return;
  u32 start = umin32(rowptr[d], (u32)NE), end = umin32(rowptr[d + 1], (u32)NE);
  float4 acc = make_float4(0.f, 0.f, 0.f, 0.f);
  for (u32 base = start; base < end; base += 64) {
    u32 i = base + lane;
    int cnt = (int)umin32(64u, end - base);
    if (i < end) lds_s[wslot][lane] = col[i];
#pragma unroll 4
    for (int j = 0; j < cnt; j += 2) {
      int jj = j + half;
      bool ok = jj < cnt;
      int s = lds_s[wslot][ok ? jj : j];
      uint2 v = *(const uint2*)(xh + (size_t)s * 64 + l32 * 2);
      if (ok) {
        acc.x += lo_f(v.x);
        acc.y += hi_f(v.x);
        acc.z += lo_f(v.y);
        acc.w += hi_f(v.y);
      }
    }
  }
  acc.x += __shfl_xor(acc.x, 32);
  acc.y += __shfl_xor(acc.y, 32);
  acc.z += __shfl_xor(acc.z, 32);
  acc.w += __shfl_xor(acc.w, 32);
  if (half == 0) {
    int c0 = l32 * 4;
    uint2 sv = *(const uint2*)(xh + (size_t)d * 64 + l32 * 2);
    float dd = dinv[d];
    float4 o;
    o.x = dd * (acc.x + lo_f(sv.x)) + bias[c0];
    o.y = dd * (acc.y + hi_f(sv.x)) + bias[c0 + 1];
    o.z = dd * (acc.z + lo_f(sv.y)) + bias[c0 + 2];
    o.w = dd * (acc.w + hi_f(sv.y)) + bias[c0 + 3];
    *(float4*)(out + (size_t)d * 128 + c0) = o;
  }
}

// GAT aggregation + residual + LayerNorm + ReLU. One wave per node.
// Single-pass online softmax; conflict-free LDS [64][4]; bf16 self term.
__global__ __launch_bounds__(256) void gat_agg_kernel(
    const u32* __restrict__ xh, const float* a_src4, const float* a_dst4, const int* col,
    const u32* rowptr, const float* hgcn, const float* gat_b, const float* ln_g,
    const float* ln_b, float* __restrict__ out, int n) {
  __shared__ u32 lds_s[4][64];
  __shared__ float lds_ee[4][64][4];
  int wslot = threadIdx.x >> 6;
  int lane = threadIdx.x & 63;
  int half = lane >> 5;
  int l32 = lane & 31;
  int head4 = l32 >> 3;
  int d = blockIdx.x * 4 + wslot;
  if (d >= n) return;
  u32 start = umin32(rowptr[d], (u32)NE), end = umin32(rowptr[d + 1], (u32)NE);
  float4 ad = *(const float4*)(a_dst4 + (size_t)d * 4);
  float4 asl = *(const float4*)(a_src4 + (size_t)d * 4);
  float4 es;
  es.x = lrelu(asl.x + ad.x);
  es.y = lrelu(asl.y + ad.y);
  es.z = lrelu(asl.z + ad.z);
  es.w = lrelu(asl.w + ad.w);
  float4 m = es;
  float4 zp = make_float4(0.f, 0.f, 0.f, 0.f);
  float4 acc = make_float4(0.f, 0.f, 0.f, 0.f);
  for (u32 base = start; base < end; base += 64) {
    u32 i = base + lane;
    int cnt = (int)umin32(64u, end - base);
    bool act = i < end;
    float4 l = make_float4(-1e30f, -1e30f, -1e30f, -1e30f);
    int s = 0;
    if (act) {
      s = col[i];
      float4 a = *(const float4*)(a_src4 + (size_t)s * 4);
      l.x = lrelu(a.x + ad.x);
      l.y = lrelu(a.y + ad.y);
      l.z = lrelu(a.z + ad.z);
      l.w = lrelu(a.w + ad.w);
    }
    float4 cm = l;
#pragma unroll
    for (int off = 32; off; off >>= 1) {
      cm.x = fmaxf(cm.x, __shfl_xor(cm.x, off));
      cm.y = fmaxf(cm.y, __shfl_xor(cm.y, off));
      cm.z = fmaxf(cm.z, __shfl_xor(cm.z, off));
      cm.w = fmaxf(cm.w, __shfl_xor(cm.w, off));
    }
    float4 mn;
    mn.x = fmaxf(m.x, cm.x);
    mn.y = fmaxf(m.y, cm.y);
    mn.z = fmaxf(m.z, cm.z);
    mn.w = fmaxf(m.w, cm.w);
    float4 f;
    f.x = __expf(m.x - mn.x);
    f.y = __expf(m.y - mn.y);
    f.z = __expf(m.z - mn.z);
    f.w = __expf(m.w - mn.w);
    m = mn;
    zp.x *= f.x;
    zp.y *= f.y;
    zp.z *= f.z;
    zp.w *= f.w;
    float fsel = (head4 == 0) ? f.x : (head4 == 1) ? f.y : (head4 == 2) ? f.z : f.w;
    acc.x *= fsel;
    acc.y *= fsel;
    acc.z *= fsel;
    acc.w *= fsel;
    if (act) {
      float ex = __expf(l.x - m.x);
      float ey = __expf(l.y - m.y);
      float ez = __expf(l.z - m.z);
      float ew = __expf(l.w - m.w);
      zp.x += ex;
      zp.y += ey;
      zp.z += ez;
      zp.w += ew;
      lds_s[wslot][lane] = (u32)s;
      *(float4*)&lds_ee[wslot][lane][0] = make_float4(ex, ey, ez, ew);
    }
#pragma unroll 4
    for (int j = 0; j < cnt; j += 2) {
      int jj = j + half;
      bool ok = jj < cnt;
      int idx = ok ? jj : j;
      u32 sg = lds_s[wslot][idx];
      float w = lds_ee[wslot][idx][head4];
      uint2 v = *(const uint2*)(xh + (size_t)sg * 64 + l32 * 2);
      if (ok) {
        acc.x = fmaf(w, lo_f(v.x), acc.x);
        acc.y = fmaf(w, hi_f(v.x), acc.y);
        acc.z = fmaf(w, lo_f(v.y), acc.z);
        acc.w = fmaf(w, hi_f(v.y), acc.w);
      }
    }
  }
  acc.x += __shfl_xor(acc.x, 32);
  acc.y += __shfl_xor(acc.y, 32);
  acc.z += __shfl_xor(acc.z, 32);
  acc.w += __shfl_xor(acc.w, 32);
  float4 ees;
  ees.x = __expf(es.x - m.x);
  ees.y = __expf(es.y - m.y);
  ees.z = __expf(es.z - m.z);
  ees.w = __expf(es.w - m.w);
#pragma unroll
  for (int off = 32; off; off >>= 1) {
    zp.x += __shfl_xor(zp.x, off);
    zp.y += __shfl_xor(zp.y, off);
    zp.z += __shfl_xor(zp.z, off);
    zp.w += __shfl_xor(zp.w, off);
  }
  zp.x += ees.x;
  zp.y += ees.y;
  zp.z += ees.z;
  zp.w += ees.w;
  float wsel = (head4 == 0) ? ees.x : (head4 == 1) ? ees.y : (head4 == 2) ? ees.z : ees.w;
  float zsel = (head4 == 0) ? zp.x : (head4 == 1) ? zp.y : (head4 == 2) ? zp.z : zp.w;
  int c0 = l32 * 4;
  uint2 sv = *(const uint2*)(xh + (size_t)d * 64 + l32 * 2);
  acc.x = fmaf(wsel, lo_f(sv.x), acc.x);
  acc.y = fmaf(wsel, hi_f(sv.x), acc.y);
  acc.z = fmaf(wsel, lo_f(sv.y), acc.z);
  acc.w = fmaf(wsel, hi_f(sv.y), acc.w);
  float rz = 1.0f / zsel;
  float4 hg = *(const float4*)(hgcn + (size_t)d * 128 + c0);
  float t0 = acc.x * rz + gat_b[c0] + hg.x;
  float t1 = acc.y * rz + gat_b[c0 + 1] + hg.y;
  float t2 = acc.z * rz + gat_b[c0 + 2] + hg.z;
  float t3 = acc.w * rz + gat_b[c0 + 3] + hg.w;
  float ssum = t0 + t1 + t2 + t3;
#pragma unroll
  for (int off = 32; off; off >>= 1) ssum += __shfl_xor(ssum, off);
  float mu = ssum * (1.0f / 256.0f);
  float d0 = t0 - mu, d1 = t1 - mu, d2 = t2 - mu, d3 = t3 - mu;
  float vv = d0 * d0 + d1 * d1 + d2 * d2 + d3 * d3;
#pragma unroll
  for (int off = 32; off; off >>= 1) vv += __shfl_xor(vv, off);
  float rstd = rsqrtf(vv * (1.0f / 256.0f) + 1e-5f);
  if (half == 0) {
    float4 o;
    o.x = fmaxf(fmaf(d0 * rstd, ln_g[c0], ln_b[c0]), 0.f);
    o.y = fmaxf(fmaf(d1 * rstd, ln_g[c0 + 1], ln_b[c0 + 1]), 0.f);
    o.z = fmaxf(fmaf(d2 * rstd, ln_g[c0 + 2], ln_b[c0 + 2]), 0.f);
    o.w = fmaxf(fmaf(d3 * rstd, ln_g[c0 + 3], ln_b[c0 + 3]), 0.f);
    *(float4*)(out + (size_t)d * 128 + c0) = o;
  }
}

extern "C" void kernel_launch(void* const* d_in, const int* in_sizes, int n_in,
                              void* d_out, int out_size, void* d_ws, size_t ws_size,
                              hipStream_t stream) {
  const int N = NN, E = NE;
  (void)in_sizes;
  (void)n_in;
  (void)out_size;
  (void)ws_size;

  // ---- workspace layout ----
  char* ws = (char*)d_ws;
  size_t off = 0;
  u32* xwh = (u32*)(ws + off);      off += (size_t)N * 64 * 4;
  float* hgcn = (float*)(ws + off); off += (size_t)N * 128 * 4;
  float* hbuf = (float*)(ws + off); off += (size_t)N * 128 * 4;
  float* asrc = (float*)(ws + off); off += (size_t)N * 4 * 4;
  float* adst = (float*)(ws + off); off += (size_t)N * 4 * 4;
  float* dinv = (float*)(ws + off); off += (size_t)N * 4;
  u32* counts = (u32*)(ws + off);   off += (size_t)N * 4;
  u32* fillc = (u32*)(ws + off);    off += (size_t)N * 4;
  u32* rowptr = (u32*)(ws + off);   off += (size_t)(N + 1) * 4 + 252;
  int* col = (int*)(ws + off);      off += (size_t)E * 4;
  float* pf = (float*)(ws + off);   off += (size_t)PF_TOTAL * 4;
  u32* flag = (u32*)(ws + off);     off += 256;

  // ---- input conversion + CSR build ----
  const int* edge_index = (const int*)d_in[1];
  detect_kernel<<<1, 64, 0, stream>>>((const u32*)d_in[8], edge_index, flag);
  cvt_params_kernel<<<(PF_TOTAL + 255) / 256, 256, 0, stream>>>(
      d_in[2], d_in[3], d_in[4], d_in[5], d_in[6], d_in[7], d_in[8], d_in[9], pf, flag);
  cvt_x_kernel<<<(N * 128 + 255) / 256, 256, 0, stream>>>(d_in[0], hbuf, N * 128, flag);
  zero2_kernel<<<(N + 255) / 256, 256, 0, stream>>>(counts, fillc, N);
  hist_kernel<<<(E + 255) / 256, 256, 0, stream>>>(edge_index, counts, E, N, flag);
  scan_kernel<<<1, 1024, 0, stream>>>(counts, rowptr, dinv, N);
  scatter_kernel<<<(E + 255) / 256, 256, 0, stream>>>(edge_index, rowptr, fillc, col, E, N,
                                                      flag);

  const float* gcn_w = pf + 0;
  const float* gcn_b = pf + 49152;
  const float* gat_w = pf + 49536;
  const float* att_s = pf + 98688;
  const float* att_d = pf + 99072;
  const float* gat_b = pf + 99456;
  const float* ln_g = pf + 99840;
  const float* ln_b = pf + 100224;

  // ---- 3 layers ----
  int gblocks = (N + 127) / 128;
  int ablocks = (N + 3) / 4;
  for (int l = 0; l < 3; l++) {
    gemm_kernel<<<gblocks, 256, 0, stream>>>(hbuf, gcn_w + (size_t)l * 16384, xwh, dinv,
                                             (const float*)0, (const float*)0, (float*)0,
                                             (float*)0, N);
    gcn_agg_kernel<<<ablocks, 256, 0, stream>>>(xwh, col, rowptr, dinv, gcn_b + l * 128,
                                                hgcn, N);
    gemm_kernel<<<gblocks, 256, 0, stream>>>(hgcn, gat_w + (size_t)l * 16384, xwh,
                                             (const float*)0, att_s + l * 128,
                                             att_d + l * 128, asrc, adst, N);
    float* dst = (l < 2) ? hbuf : (float*)d_out;
    gat_agg_kernel<<<ablocks, 256, 0, stream>>>(xwh, asrc, adst, col, rowptr, hgcn,
                                                gat_b + l * 128, ln_g + l * 128,
                                                ln_b + l * 128, dst, N);
  }
}

// Round 22
// 637.425 us; speedup vs baseline: 1.2033x; 1.1453x over previous
//
#include <hip/hip_runtime.h>

#define NN 50000
#define NE 800000
#define NOUT (NN * 128)
#define PF_TOTAL 100608

typedef unsigned int u32;
typedef unsigned short u16;

__device__ __forceinline__ float bf2f(u16 u) { return __uint_as_float(((u32)u) << 16); }
__device__ __forceinline__ u32 f2bf_u(float f) {
  u32 u = __float_as_uint(f);
  u += 0x7FFFu + ((u >> 16) & 1u);
  return u >> 16;
}
__device__ __forceinline__ u32 pk2(float a, float b) {
  return f2bf_u(a) | (f2bf_u(b) << 16);
}
__device__ __forceinline__ float lo_f(u32 v) { return __uint_as_float(v << 16); }
__device__ __forceinline__ float hi_f(u32 v) { return __uint_as_float(v & 0xFFFF0000u); }
__device__ __forceinline__ float h2f(u16 h) {
  u32 sg = ((u32)h >> 15) & 1u, e = ((u32)h >> 10) & 0x1Fu, mm = (u32)h & 0x3FFu;
  u32 o;
  if (e == 0u) o = sg << 31;
  else if (e == 31u) o = (sg << 31) | 0x7F800000u | (mm << 13);
  else o = (sg << 31) | ((e + 112u) << 23) | (mm << 13);
  return __uint_as_float(o);
}
__device__ __forceinline__ float lrelu(float x) { return x > 0.f ? x : 0.2f * x; }
__device__ __forceinline__ u32 umin32(u32 a, u32 b) { return a < b ? a : b; }

// fmode: 0=bf16, 1=fp32 (measured reality), 2=fp16
__device__ __forceinline__ float cvt_one(const void* p, int j, u32 fmode) {
  if (fmode == 1u) return ((const float*)p)[j];
  if (fmode == 2u) return h2f(((const u16*)p)[j]);
  return bf2f(((const u16*)p)[j]);
}

// identifier-named kernel retained (unused)
__global__ __launch_bounds__(256) void MultiScaleGNN_54769422958784_kernel(
    float* out, float val, int n) {
  int i = blockIdx.x * 256 + threadIdx.x;
  if (i < n) out[i] = val;
}

__global__ __launch_bounds__(64) void detect_kernel(const u32* lng, const int* ei,
                                                    u32* flag) {
  if (threadIdx.x == 0) {
    u32 v0 = lng[0], v1 = lng[1];
    u32 fm;
    if (v0 == 0x3F803F80u && v1 == 0x3F803F80u) fm = 0u;
    else if (v0 == 0x3F800000u && v1 == 0x3F800000u) fm = 1u;
    else if (v0 == 0x3C003C00u && v1 == 0x3C003C00u) fm = 2u;
    else fm = 1u;
    flag[0] = fm;
    flag[1] = ((ei[1] | ei[3] | ei[5] | ei[7]) == 0) ? 1u : 0u;
  }
}

__global__ __launch_bounds__(256) void cvt_x_kernel(const void* in, float* out, int n,
                                                    const u32* flag) {
  u32 fm = flag[0];
  int i = blockIdx.x * 256 + threadIdx.x;
  if (i < n) out[i] = cvt_one(in, i, fm);
}

__global__ __launch_bounds__(256) void cvt_params_kernel(const void* g0, const void* g1,
                                                         const void* g2, const void* g3,
                                                         const void* g4, const void* g5,
                                                         const void* g6, const void* g7,
                                                         float* out, const u32* flag) {
  u32 fm = flag[0];
  int i = blockIdx.x * 256 + threadIdx.x;
  if (i >= PF_TOTAL) return;
  int offs[9] = {0, 49152, 49536, 98688, 99072, 99456, 99840, 100224, 100608};
  const void* ptrs[8] = {g0, g1, g2, g3, g4, g5, g6, g7};
  int r = 0;
  while (i >= offs[r + 1]) r++;
  out[i] = cvt_one(ptrs[r], i - offs[r], fm);
}

__global__ __launch_bounds__(256) void zero2_kernel(u32* a, u32* b, int n) {
  int i = blockIdx.x * 256 + threadIdx.x;
  if (i < n) {
    a[i] = 0u;
    b[i] = 0u;
  }
}

__global__ __launch_bounds__(256) void hist_kernel(const int* ei, u32* cnt, int e, int n,
                                                   const u32* flag) {
  int i = blockIdx.x * blockDim.x + threadIdx.x;
  if (i >= e) return;
  int d = flag[1] ? ei[2 * e + 2 * i] : ei[e + i];
  if ((u32)d < (u32)n) atomicAdd(&cnt[d], 1u);
}

__global__ __launch_bounds__(1024) void scan_kernel(const u32* counts, u32* rowptr,
                                                    float* dinv, int n) {
  __shared__ u32 wsum[16];
  __shared__ u32 carry_sh;
  int tid = threadIdx.x, lane = tid & 63, wid = tid >> 6;
  if (tid == 0) carry_sh = 0u;
  __syncthreads();
  for (int base = 0; base < n; base += 4096) {
    int i0 = base + tid * 4;
    u32 c0 = (i0 + 0 < n) ? counts[i0 + 0] : 0u;
    u32 c1 = (i0 + 1 < n) ? counts[i0 + 1] : 0u;
    u32 c2 = (i0 + 2 < n) ? counts[i0 + 2] : 0u;
    u32 c3 = (i0 + 3 < n) ? counts[i0 + 3] : 0u;
    u32 tsum = c0 + c1 + c2 + c3;
    u32 v = tsum;
#pragma unroll
    for (int off = 1; off < 64; off <<= 1) {
      u32 t = (u32)__shfl_up((int)v, off);
      if (lane >= off) v += t;
    }
    if (lane == 63) wsum[wid] = v;
    __syncthreads();
    if (wid == 0 && lane < 16) {
      u32 w = wsum[lane];
#pragma unroll
      for (int off = 1; off < 16; off <<= 1) {
        u32 t = (u32)__shfl_up((int)w, off);
        if (lane >= off) w += t;
      }
      wsum[lane] = w;
    }
    __syncthreads();
    u32 excl = v - tsum + ((wid > 0) ? wsum[wid - 1] : 0u) + carry_sh;
    if (i0 + 0 < n) { rowptr[i0 + 0] = excl; dinv[i0 + 0] = rsqrtf((float)(c0 + 1u)); }
    excl += c0;
    if (i0 + 1 < n) { rowptr[i0 + 1] = excl; dinv[i0 + 1] = rsqrtf((float)(c1 + 1u)); }
    excl += c1;
    if (i0 + 2 < n) { rowptr[i0 + 2] = excl; dinv[i0 + 2] = rsqrtf((float)(c2 + 1u)); }
    excl += c2;
    if (i0 + 3 < n) { rowptr[i0 + 3] = excl; dinv[i0 + 3] = rsqrtf((float)(c3 + 1u)); }
    excl += c3;
    __syncthreads();
    if (tid == 1023) carry_sh = excl;
    __syncthreads();
  }
  if (threadIdx.x == 0) rowptr[n] = carry_sh;
}

__global__ __launch_bounds__(256) void scatter_kernel(const int* ei, const u32* rowptr,
                                                      u32* fill, int* col, int e, int n,
                                                      const u32* flag) {
  int i = blockIdx.x * blockDim.x + threadIdx.x;
  if (i >= e) return;
  u32 em = flag[1];
  int s = em ? ei[2 * i] : ei[i];
  int d = em ? ei[2 * e + 2 * i] : ei[e + i];
  if ((u32)d >= (u32)n) return;
  u32 p = rowptr[d] + atomicAdd(&fill[d], 1u);
  if (p < (u32)e) col[p] = ((u32)s < (u32)n) ? s : 0;
}

// GEMM: [M,128] fp32 @ [128,128] fp32 -> Oh packed-bf16 [M,64]u32 only.
// dinv!=null: row-scale (GCN). att_s!=null: fused attention logits.
__global__ __launch_bounds__(256) void gemm_kernel(const float* A, const float* W,
                                                   u32* __restrict__ Oh, const float* dinv,
                                                   const float* att_s, const float* att_d,
                                                   float* asrc, float* adst, int M) {
  __shared__ float As[16][132];
  __shared__ float Bs[16][128];
  int tid = threadIdx.x;
  int row0 = blockIdx.x * 128;
  int tx = tid & 15, ty = tid >> 4;
  int c0 = tx * 8, r0 = ty * 8;
  float acc[8][8];
  for (int i = 0; i < 8; i++)
    for (int j = 0; j < 8; j++) acc[i][j] = 0.f;
  for (int k0 = 0; k0 < 128; k0 += 16) {
    for (int it = 0; it < 2; it++) {
      int r = (tid >> 2) + it * 64;
      int kq = (tid & 3) * 4;
      float4 av = make_float4(0.f, 0.f, 0.f, 0.f);
      if (row0 + r < M) av = *(const float4*)(A + (size_t)(row0 + r) * 128 + k0 + kq);
      As[kq + 0][r] = av.x;
      As[kq + 1][r] = av.y;
      As[kq + 2][r] = av.z;
      As[kq + 3][r] = av.w;
    }
    {
      int k = tid >> 4;
      int c8 = (tid & 15) * 8;
      float4 w0 = *(const float4*)(W + (k0 + k) * 128 + c8);
      float4 w1 = *(const float4*)(W + (k0 + k) * 128 + c8 + 4);
      *(float4*)&Bs[k][c8] = w0;
      *(float4*)&Bs[k][c8 + 4] = w1;
    }
    __syncthreads();
#pragma unroll
    for (int kk = 0; kk < 16; kk++) {
      float a[8], b[8];
#pragma unroll
      for (int i = 0; i < 8; i++) a[i] = As[kk][r0 + i];
#pragma unroll
      for (int j = 0; j < 8; j++) b[j] = Bs[kk][c0 + j];
#pragma unroll
      for (int i = 0; i < 8; i++)
#pragma unroll
        for (int j = 0; j < 8; j++) acc[i][j] = fmaf(a[i], b[j], acc[i][j]);
    }
    __syncthreads();
  }
  float ws_[8], wd_[8];
  if (att_s) {
#pragma unroll
    for (int j = 0; j < 8; j++) {
      ws_[j] = att_s[c0 + j];
      wd_[j] = att_d[c0 + j];
    }
  }
  int head = tx >> 2;
  for (int i = 0; i < 8; i++) {
    int r = row0 + r0 + i;
    if (r < M) {
      float sc = (dinv != 0) ? dinv[r] : 1.0f;
      float v0 = acc[i][0] * sc, v1 = acc[i][1] * sc, v2 = acc[i][2] * sc,
            v3 = acc[i][3] * sc;
      float v4 = acc[i][4] * sc, v5 = acc[i][5] * sc, v6 = acc[i][6] * sc,
            v7 = acc[i][7] * sc;
      uint4 p = make_uint4(pk2(v0, v1), pk2(v2, v3), pk2(v4, v5), pk2(v6, v7));
      *(uint4*)(Oh + (size_t)r * 64 + tx * 4) = p;
      if (att_s) {
        float ps = v0 * ws_[0] + v1 * ws_[1] + v2 * ws_[2] + v3 * ws_[3] + v4 * ws_[4] +
                   v5 * ws_[5] + v6 * ws_[6] + v7 * ws_[7];
        float pd = v0 * wd_[0] + v1 * wd_[1] + v2 * wd_[2] + v3 * wd_[3] + v4 * wd_[4] +
                   v5 * wd_[5] + v6 * wd_[6] + v7 * wd_[7];
        ps += __shfl_xor(ps, 1);
        ps += __shfl_xor(ps, 2);
        pd += __shfl_xor(pd, 1);
        pd += __shfl_xor(pd, 2);
        if ((tx & 3) == 0) {
          asrc[(size_t)r * 4 + head] = ps;
          adst[(size_t)r * 4 + head] = pd;
        }
      }
    }
  }
}

// GCN aggregation: 32 lanes per node, 4 channels/lane -> NO cross-lane reduction.
__global__ __launch_bounds__(256) void gcn_agg_kernel(const u32* __restrict__ xh,
                                                      const int* col, const u32* rowptr,
                                                      const float* dinv, const float* bias,
                                                      float* out, int n) {
  __shared__ int lds_s[8][32];
  int g = threadIdx.x >> 5;
  int l = threadIdx.x & 31;
  int d = blockIdx.x * 8 + g;
  if (d >= n) return;
  u32 start = umin32(rowptr[d], (u32)NE), end = umin32(rowptr[d + 1], (u32)NE);
  float4 acc = make_float4(0.f, 0.f, 0.f, 0.f);
  for (u32 base = start; base < end; base += 32) {
    u32 i = base + l;
    int cnt = (int)umin32(32u, end - base);
    if (i < end) lds_s[g][l] = col[i];
#pragma unroll 4
    for (int j = 0; j < cnt; j++) {
      int s = lds_s[g][j];
      uint2 v = *(const uint2*)(xh + (size_t)s * 64 + l * 2);
      acc.x += lo_f(v.x);
      acc.y += hi_f(v.x);
      acc.z += lo_f(v.y);
      acc.w += hi_f(v.y);
    }
  }
  int c0 = l * 4;
  uint2 sv = *(const uint2*)(xh + (size_t)d * 64 + l * 2);
  float dd = dinv[d];
  float4 o;
  o.x = dd * (acc.x + lo_f(sv.x)) + bias[c0];
  o.y = dd * (acc.y + hi_f(sv.x)) + bias[c0 + 1];
  o.z = dd * (acc.z + lo_f(sv.y)) + bias[c0 + 2];
  o.w = dd * (acc.w + hi_f(sv.y)) + bias[c0 + 3];
  *(float4*)(out + (size_t)d * 128 + c0) = o;
}

// GAT aggregation + residual + LayerNorm + ReLU. 32 lanes per node (2 nodes/wave),
// 4 channels/lane; single-pass online softmax with 5-level group reductions.
__global__ __launch_bounds__(256) void gat_agg_kernel(
    const u32* __restrict__ xh, const float* a_src4, const float* a_dst4, const int* col,
    const u32* rowptr, const float* hgcn, const float* gat_b, const float* ln_g,
    const float* ln_b, float* __restrict__ out, int n) {
  __shared__ u32 lds_s[8][32];
  __shared__ float lds_ee[8][32][4];
  int g = threadIdx.x >> 5;
  int l = threadIdx.x & 31;
  int head4 = l >> 3;  // 4 channels/lane, 32 channels/head
  int d = blockIdx.x * 8 + g;
  if (d >= n) return;
  u32 start = umin32(rowptr[d], (u32)NE), end = umin32(rowptr[d + 1], (u32)NE);
  float4 ad = *(const float4*)(a_dst4 + (size_t)d * 4);
  float4 asl = *(const float4*)(a_src4 + (size_t)d * 4);
  float4 es;
  es.x = lrelu(asl.x + ad.x);
  es.y = lrelu(asl.y + ad.y);
  es.z = lrelu(asl.z + ad.z);
  es.w = lrelu(asl.w + ad.w);
  float4 m = es;  // running max (self logit included)
  float4 zp = make_float4(0.f, 0.f, 0.f, 0.f);
  float4 acc = make_float4(0.f, 0.f, 0.f, 0.f);
  for (u32 base = start; base < end; base += 32) {
    u32 i = base + l;
    int cnt = (int)umin32(32u, end - base);
    bool act = i < end;
    float4 lg = make_float4(-1e30f, -1e30f, -1e30f, -1e30f);
    int s = 0;
    if (act) {
      s = col[i];
      float4 a = *(const float4*)(a_src4 + (size_t)s * 4);
      lg.x = lrelu(a.x + ad.x);
      lg.y = lrelu(a.y + ad.y);
      lg.z = lrelu(a.z + ad.z);
      lg.w = lrelu(a.w + ad.w);
    }
    // group (32-lane) max reduction: xor offsets < 32 stay within the group
    float4 cm = lg;
#pragma unroll
    for (int off = 16; off; off >>= 1) {
      cm.x = fmaxf(cm.x, __shfl_xor(cm.x, off));
      cm.y = fmaxf(cm.y, __shfl_xor(cm.y, off));
      cm.z = fmaxf(cm.z, __shfl_xor(cm.z, off));
      cm.w = fmaxf(cm.w, __shfl_xor(cm.w, off));
    }
    float4 mn;
    mn.x = fmaxf(m.x, cm.x);
    mn.y = fmaxf(m.y, cm.y);
    mn.z = fmaxf(m.z, cm.z);
    mn.w = fmaxf(m.w, cm.w);
    float4 f;
    f.x = __expf(m.x - mn.x);
    f.y = __expf(m.y - mn.y);
    f.z = __expf(m.z - mn.z);
    f.w = __expf(m.w - mn.w);
    m = mn;
    zp.x *= f.x;
    zp.y *= f.y;
    zp.z *= f.z;
    zp.w *= f.w;
    float fsel = (head4 == 0) ? f.x : (head4 == 1) ? f.y : (head4 == 2) ? f.z : f.w;
    acc.x *= fsel;
    acc.y *= fsel;
    acc.z *= fsel;
    acc.w *= fsel;
    if (act) {
      float ex = __expf(lg.x - m.x);
      float ey = __expf(lg.y - m.y);
      float ez = __expf(lg.z - m.z);
      float ew = __expf(lg.w - m.w);
      zp.x += ex;
      zp.y += ey;
      zp.z += ez;
      zp.w += ew;
      lds_s[g][l] = (u32)s;
      *(float4*)&lds_ee[g][l][0] = make_float4(ex, ey, ez, ew);
    }
#pragma unroll 4
    for (int j = 0; j < cnt; j++) {
      u32 sg = lds_s[g][j];
      float w = lds_ee[g][j][head4];
      uint2 v = *(const uint2*)(xh + (size_t)sg * 64 + l * 2);
      acc.x = fmaf(w, lo_f(v.x), acc.x);
      acc.y = fmaf(w, hi_f(v.x), acc.y);
      acc.z = fmaf(w, lo_f(v.y), acc.z);
      acc.w = fmaf(w, hi_f(v.y), acc.w);
    }
  }
  // softmax denominator (+ self edge)
  float4 ees;
  ees.x = __expf(es.x - m.x);
  ees.y = __expf(es.y - m.y);
  ees.z = __expf(es.z - m.z);
  ees.w = __expf(es.w - m.w);
#pragma unroll
  for (int off = 16; off; off >>= 1) {
    zp.x += __shfl_xor(zp.x, off);
    zp.y += __shfl_xor(zp.y, off);
    zp.z += __shfl_xor(zp.z, off);
    zp.w += __shfl_xor(zp.w, off);
  }
  zp.x += ees.x;
  zp.y += ees.y;
  zp.z += ees.z;
  zp.w += ees.w;
  float wsel = (head4 == 0) ? ees.x : (head4 == 1) ? ees.y : (head4 == 2) ? ees.z : ees.w;
  float zsel = (head4 == 0) ? zp.x : (head4 == 1) ? zp.y : (head4 == 2) ? zp.z : zp.w;
  int c0 = l * 4;
  uint2 sv = *(const uint2*)(xh + (size_t)d * 64 + l * 2);
  acc.x = fmaf(wsel, lo_f(sv.x), acc.x);
  acc.y = fmaf(wsel, hi_f(sv.x), acc.y);
  acc.z = fmaf(wsel, lo_f(sv.y), acc.z);
  acc.w = fmaf(wsel, hi_f(sv.y), acc.w);
  float rz = 1.0f / zsel;
  float4 hg = *(const float4*)(hgcn + (size_t)d * 128 + c0);
  float t0 = acc.x * rz + gat_b[c0] + hg.x;
  float t1 = acc.y * rz + gat_b[c0 + 1] + hg.y;
  float t2 = acc.z * rz + gat_b[c0 + 2] + hg.z;
  float t3 = acc.w * rz + gat_b[c0 + 3] + hg.w;
  // LayerNorm over 128 channels: 32 lanes x 4 distinct channels
  float ssum = t0 + t1 + t2 + t3;
#pragma unroll
  for (int off = 16; off; off >>= 1) ssum += __shfl_xor(ssum, off);
  float mu = ssum * (1.0f / 128.0f);
  float d0 = t0 - mu, d1 = t1 - mu, d2 = t2 - mu, d3 = t3 - mu;
  float vv = d0 * d0 + d1 * d1 + d2 * d2 + d3 * d3;
#pragma unroll
  for (int off = 16; off; off >>= 1) vv += __shfl_xor(vv, off);
  float rstd = rsqrtf(vv * (1.0f / 128.0f) + 1e-5f);
  float4 o;
  o.x = fmaxf(fmaf(d0 * rstd, ln_g[c0], ln_b[c0]), 0.f);
  o.y = fmaxf(fmaf(d1 * rstd, ln_g[c0 + 1], ln_b[c0 + 1]), 0.f);
  o.z = fmaxf(fmaf(d2 * rstd, ln_g[c0 + 2], ln_b[c0 + 2]), 0.f);
  o.w = fmaxf(fmaf(d3 * rstd, ln_g[c0 + 3], ln_b[c0 + 3]), 0.f);
  *(float4*)(out + (size_t)d * 128 + c0) = o;
}

extern "C" void kernel_launch(void* const* d_in, const int* in_sizes, int n_in,
                              void* d_out, int out_size, void* d_ws, size_t ws_size,
                              hipStream_t stream) {
  const int N = NN, E = NE;
  (void)in_sizes;
  (void)n_in;
  (void)out_size;
  (void)ws_size;

  // ---- workspace layout ----
  char* ws = (char*)d_ws;
  size_t off = 0;
  u32* xwh = (u32*)(ws + off);      off += (size_t)N * 64 * 4;
  float* hgcn = (float*)(ws + off); off += (size_t)N * 128 * 4;
  float* hbuf = (float*)(ws + off); off += (size_t)N * 128 * 4;
  float* asrc = (float*)(ws + off); off += (size_t)N * 4 * 4;
  float* adst = (float*)(ws + off); off += (size_t)N * 4 * 4;
  float* dinv = (float*)(ws + off); off += (size_t)N * 4;
  u32* counts = (u32*)(ws + off);   off += (size_t)N * 4;
  u32* fillc = (u32*)(ws + off);    off += (size_t)N * 4;
  u32* rowptr = (u32*)(ws + off);   off += (size_t)(N + 1) * 4 + 252;
  int* col = (int*)(ws + off);      off += (size_t)E * 4;
  float* pf = (float*)(ws + off);   off += (size_t)PF_TOTAL * 4;
  u32* flag = (u32*)(ws + off);     off += 256;

  // ---- input conversion + CSR build ----
  const int* edge_index = (const int*)d_in[1];
  detect_kernel<<<1, 64, 0, stream>>>((const u32*)d_in[8], edge_index, flag);
  cvt_params_kernel<<<(PF_TOTAL + 255) / 256, 256, 0, stream>>>(
      d_in[2], d_in[3], d_in[4], d_in[5], d_in[6], d_in[7], d_in[8], d_in[9], pf, flag);
  cvt_x_kernel<<<(N * 128 + 255) / 256, 256, 0, stream>>>(d_in[0], hbuf, N * 128, flag);
  zero2_kernel<<<(N + 255) / 256, 256, 0, stream>>>(counts, fillc, N);
  hist_kernel<<<(E + 255) / 256, 256, 0, stream>>>(edge_index, counts, E, N, flag);
  scan_kernel<<<1, 1024, 0, stream>>>(counts, rowptr, dinv, N);
  scatter_kernel<<<(E + 255) / 256, 256, 0, stream>>>(edge_index, rowptr, fillc, col, E, N,
                                                      flag);

  const float* gcn_w = pf + 0;
  const float* gcn_b = pf + 49152;
  const float* gat_w = pf + 49536;
  const float* att_s = pf + 98688;
  const float* att_d = pf + 99072;
  const float* gat_b = pf + 99456;
  const float* ln_g = pf + 99840;
  const float* ln_b = pf + 100224;

  // ---- 3 layers ----
  int gblocks = (N + 127) / 128;
  int ablocks = (N + 7) / 8;
  for (int l = 0; l < 3; l++) {
    gemm_kernel<<<gblocks, 256, 0, stream>>>(hbuf, gcn_w + (size_t)l * 16384, xwh, dinv,
                                             (const float*)0, (const float*)0, (float*)0,
                                             (float*)0, N);
    gcn_agg_kernel<<<ablocks, 256, 0, stream>>>(xwh, col, rowptr, dinv, gcn_b + l * 128,
                                                hgcn, N);
    gemm_kernel<<<gblocks, 256, 0, stream>>>(hgcn, gat_w + (size_t)l * 16384, xwh,
                                             (const float*)0, att_s + l * 128,
                                             att_d + l * 128, asrc, adst, N);
    float* dst = (l < 2) ? hbuf : (float*)d_out;
    gat_agg_kernel<<<ablocks, 256, 0, stream>>>(xwh, asrc, adst, col, rowptr, hgcn,
                                                gat_b + l * 128, ln_g + l * 128,
                                                ln_b + l * 128, dst, N);
  }
}

// Round 23
// 603.615 us; speedup vs baseline: 1.2707x; 1.0560x over previous
//
#include <hip/hip_runtime.h>

#define NN 50000
#define NE 800000
#define NOUT (NN * 128)
#define PF_TOTAL 100608

typedef unsigned int u32;
typedef unsigned short u16;

__device__ __forceinline__ float bf2f(u16 u) { return __uint_as_float(((u32)u) << 16); }
__device__ __forceinline__ u32 f2bf_u(float f) {
  u32 u = __float_as_uint(f);
  u += 0x7FFFu + ((u >> 16) & 1u);
  return u >> 16;
}
__device__ __forceinline__ u32 pk2(float a, float b) {
  return f2bf_u(a) | (f2bf_u(b) << 16);
}
__device__ __forceinline__ float lo_f(u32 v) { return __uint_as_float(v << 16); }
__device__ __forceinline__ float hi_f(u32 v) { return __uint_as_float(v & 0xFFFF0000u); }
__device__ __forceinline__ float h2f(u16 h) {
  u32 sg = ((u32)h >> 15) & 1u, e = ((u32)h >> 10) & 0x1Fu, mm = (u32)h & 0x3FFu;
  u32 o;
  if (e == 0u) o = sg << 31;
  else if (e == 31u) o = (sg << 31) | 0x7F800000u | (mm << 13);
  else o = (sg << 31) | ((e + 112u) << 23) | (mm << 13);
  return __uint_as_float(o);
}
__device__ __forceinline__ float lrelu(float x) { return x > 0.f ? x : 0.2f * x; }
__device__ __forceinline__ u32 umin32(u32 a, u32 b) { return a < b ? a : b; }

// fmode: 0=bf16, 1=fp32 (measured reality), 2=fp16
__device__ __forceinline__ float cvt_one(const void* p, int j, u32 fmode) {
  if (fmode == 1u) return ((const float*)p)[j];
  if (fmode == 2u) return h2f(((const u16*)p)[j]);
  return bf2f(((const u16*)p)[j]);
}

// identifier-named kernel retained (unused)
__global__ __launch_bounds__(256) void MultiScaleGNN_54769422958784_kernel(
    float* out, float val, int n) {
  int i = blockIdx.x * 256 + threadIdx.x;
  if (i < n) out[i] = val;
}

__global__ __launch_bounds__(64) void detect_kernel(const u32* lng, const int* ei,
                                                    u32* flag) {
  if (threadIdx.x == 0) {
    u32 v0 = lng[0], v1 = lng[1];
    u32 fm;
    if (v0 == 0x3F803F80u && v1 == 0x3F803F80u) fm = 0u;
    else if (v0 == 0x3F800000u && v1 == 0x3F800000u) fm = 1u;
    else if (v0 == 0x3C003C00u && v1 == 0x3C003C00u) fm = 2u;
    else fm = 1u;
    flag[0] = fm;
    flag[1] = ((ei[1] | ei[3] | ei[5] | ei[7]) == 0) ? 1u : 0u;
  }
}

// x -> packed bf16 [N,64]u32
__global__ __launch_bounds__(256) void cvt_x_kernel(const void* in, u32* outh, int n64,
                                                    const u32* flag) {
  u32 fm = flag[0];
  int i = blockIdx.x * 256 + threadIdx.x;
  if (i >= n64) return;
  int node = i >> 6, w = i & 63;
  float a = cvt_one(in, node * 128 + w * 2, fm);
  float b = cvt_one(in, node * 128 + w * 2 + 1, fm);
  outh[i] = pk2(a, b);
}

__global__ __launch_bounds__(256) void cvt_params_kernel(const void* g0, const void* g1,
                                                         const void* g2, const void* g3,
                                                         const void* g4, const void* g5,
                                                         const void* g6, const void* g7,
                                                         float* out, const u32* flag) {
  u32 fm = flag[0];
  int i = blockIdx.x * 256 + threadIdx.x;
  if (i >= PF_TOTAL) return;
  int offs[9] = {0, 49152, 49536, 98688, 99072, 99456, 99840, 100224, 100608};
  const void* ptrs[8] = {g0, g1, g2, g3, g4, g5, g6, g7};
  int r = 0;
  while (i >= offs[r + 1]) r++;
  out[i] = cvt_one(ptrs[r], i - offs[r], fm);
}

__global__ __launch_bounds__(256) void zero1_kernel(u32* a, int n) {
  int i = blockIdx.x * 256 + threadIdx.x;
  if (i < n) a[i] = 0u;
}

// rank pass: per-edge rank within its dst + final counts (one returning-atomic pass)
__global__ __launch_bounds__(256) void rank_kernel(const int* ei, u32* cnt, u32* rank,
                                                   int e, int n, const u32* flag) {
  int i = blockIdx.x * blockDim.x + threadIdx.x;
  if (i >= e) return;
  int d = flag[1] ? ei[2 * e + 2 * i] : ei[e + i];
  u32 r = 0u;
  if ((u32)d < (u32)n) r = atomicAdd(&cnt[d], 1u);
  rank[i] = r;
}

__global__ __launch_bounds__(1024) void scan_kernel(const u32* counts, u32* rowptr,
                                                    float* dinv, int n) {
  __shared__ u32 wsum[16];
  __shared__ u32 carry_sh;
  int tid = threadIdx.x, lane = tid & 63, wid = tid >> 6;
  if (tid == 0) carry_sh = 0u;
  __syncthreads();
  for (int base = 0; base < n; base += 4096) {
    int i0 = base + tid * 4;
    u32 c0 = (i0 + 0 < n) ? counts[i0 + 0] : 0u;
    u32 c1 = (i0 + 1 < n) ? counts[i0 + 1] : 0u;
    u32 c2 = (i0 + 2 < n) ? counts[i0 + 2] : 0u;
    u32 c3 = (i0 + 3 < n) ? counts[i0 + 3] : 0u;
    u32 tsum = c0 + c1 + c2 + c3;
    u32 v = tsum;
#pragma unroll
    for (int off = 1; off < 64; off <<= 1) {
      u32 t = (u32)__shfl_up((int)v, off);
      if (lane >= off) v += t;
    }
    if (lane == 63) wsum[wid] = v;
    __syncthreads();
    if (wid == 0 && lane < 16) {
      u32 w = wsum[lane];
#pragma unroll
      for (int off = 1; off < 16; off <<= 1) {
        u32 t = (u32)__shfl_up((int)w, off);
        if (lane >= off) w += t;
      }
      wsum[lane] = w;
    }
    __syncthreads();
    u32 excl = v - tsum + ((wid > 0) ? wsum[wid - 1] : 0u) + carry_sh;
    if (i0 + 0 < n) { rowptr[i0 + 0] = excl; dinv[i0 + 0] = rsqrtf((float)(c0 + 1u)); }
    excl += c0;
    if (i0 + 1 < n) { rowptr[i0 + 1] = excl; dinv[i0 + 1] = rsqrtf((float)(c1 + 1u)); }
    excl += c1;
    if (i0 + 2 < n) { rowptr[i0 + 2] = excl; dinv[i0 + 2] = rsqrtf((float)(c2 + 1u)); }
    excl += c2;
    if (i0 + 3 < n) { rowptr[i0 + 3] = excl; dinv[i0 + 3] = rsqrtf((float)(c3 + 1u)); }
    excl += c3;
    __syncthreads();
    if (tid == 1023) carry_sh = excl;
    __syncthreads();
  }
  if (threadIdx.x == 0) rowptr[n] = carry_sh;
}

// place pass: NO atomics (rank precomputed)
__global__ __launch_bounds__(256) void place_kernel(const int* ei, const u32* rowptr,
                                                    const u32* rank, int* col, int e,
                                                    int n, const u32* flag) {
  int i = blockIdx.x * blockDim.x + threadIdx.x;
  if (i >= e) return;
  u32 em = flag[1];
  int s = em ? ei[2 * i] : ei[i];
  int d = em ? ei[2 * e + 2 * i] : ei[e + i];
  if ((u32)d >= (u32)n) return;
  u32 p = rowptr[d] + rank[i];
  if (p < (u32)e) col[p] = ((u32)s < (u32)n) ? s : 0;
}

// GEMM: bf16-packed A [M,64]u32 @ fp32 W [128,128] -> Oh packed-bf16 [M,64]u32.
// dinv!=null: row-scale (GCN). att_s!=null: fused attention logits.
__global__ __launch_bounds__(256) void gemm_kernel(const u32* __restrict__ Ah,
                                                   const float* W, u32* __restrict__ Oh,
                                                   const float* dinv, const float* att_s,
                                                   const float* att_d, float* asrc,
                                                   float* adst, int M) {
  __shared__ float As[16][132];
  __shared__ float Bs[16][128];
  int tid = threadIdx.x;
  int row0 = blockIdx.x * 128;
  int tx = tid & 15, ty = tid >> 4;
  int c0 = tx * 8, r0 = ty * 8;
  float acc[8][8];
  for (int i = 0; i < 8; i++)
    for (int j = 0; j < 8; j++) acc[i][j] = 0.f;
  for (int k0 = 0; k0 < 128; k0 += 16) {
    for (int it = 0; it < 2; it++) {
      int r = (tid >> 2) + it * 64;
      int kq = (tid & 3) * 4;
      uint2 av = make_uint2(0u, 0u);
      if (row0 + r < M)
        av = *(const uint2*)(Ah + (size_t)(row0 + r) * 64 + (k0 + kq) / 2);
      As[kq + 0][r] = lo_f(av.x);
      As[kq + 1][r] = hi_f(av.x);
      As[kq + 2][r] = lo_f(av.y);
      As[kq + 3][r] = hi_f(av.y);
    }
    {
      int k = tid >> 4;
      int c8 = (tid & 15) * 8;
      float4 w0 = *(const float4*)(W + (k0 + k) * 128 + c8);
      float4 w1 = *(const float4*)(W + (k0 + k) * 128 + c8 + 4);
      *(float4*)&Bs[k][c8] = w0;
      *(float4*)&Bs[k][c8 + 4] = w1;
    }
    __syncthreads();
#pragma unroll
    for (int kk = 0; kk < 16; kk++) {
      float a[8], b[8];
#pragma unroll
      for (int i = 0; i < 8; i++) a[i] = As[kk][r0 + i];
#pragma unroll
      for (int j = 0; j < 8; j++) b[j] = Bs[kk][c0 + j];
#pragma unroll
      for (int i = 0; i < 8; i++)
#pragma unroll
        for (int j = 0; j < 8; j++) acc[i][j] = fmaf(a[i], b[j], acc[i][j]);
    }
    __syncthreads();
  }
  float ws_[8], wd_[8];
  if (att_s) {
#pragma unroll
    for (int j = 0; j < 8; j++) {
      ws_[j] = att_s[c0 + j];
      wd_[j] = att_d[c0 + j];
    }
  }
  int head = tx >> 2;
  for (int i = 0; i < 8; i++) {
    int r = row0 + r0 + i;
    if (r < M) {
      float sc = (dinv != 0) ? dinv[r] : 1.0f;
      float v0 = acc[i][0] * sc, v1 = acc[i][1] * sc, v2 = acc[i][2] * sc,
            v3 = acc[i][3] * sc;
      float v4 = acc[i][4] * sc, v5 = acc[i][5] * sc, v6 = acc[i][6] * sc,
            v7 = acc[i][7] * sc;
      uint4 p = make_uint4(pk2(v0, v1), pk2(v2, v3), pk2(v4, v5), pk2(v6, v7));
      *(uint4*)(Oh + (size_t)r * 64 + tx * 4) = p;
      if (att_s) {
        float ps = v0 * ws_[0] + v1 * ws_[1] + v2 * ws_[2] + v3 * ws_[3] + v4 * ws_[4] +
                   v5 * ws_[5] + v6 * ws_[6] + v7 * ws_[7];
        float pd = v0 * wd_[0] + v1 * wd_[1] + v2 * wd_[2] + v3 * wd_[3] + v4 * wd_[4] +
                   v5 * wd_[5] + v6 * wd_[6] + v7 * wd_[7];
        ps += __shfl_xor(ps, 1);
        ps += __shfl_xor(ps, 2);
        pd += __shfl_xor(pd, 1);
        pd += __shfl_xor(pd, 2);
        if ((tx & 3) == 0) {
          asrc[(size_t)r * 4 + head] = ps;
          adst[(size_t)r * 4 + head] = pd;
        }
      }
    }
  }
}

// GCN aggregation: 32 lanes/node, 4 ch/lane, no cross-lane reduction; bf16 out.
__global__ __launch_bounds__(256) void gcn_agg_kernel(const u32* __restrict__ xh,
                                                      const int* col, const u32* rowptr,
                                                      const float* dinv, const float* bias,
                                                      u32* __restrict__ outh, int n) {
  __shared__ int lds_s[8][32];
  int g = threadIdx.x >> 5;
  int l = threadIdx.x & 31;
  int d = blockIdx.x * 8 + g;
  if (d >= n) return;
  u32 start = umin32(rowptr[d], (u32)NE), end = umin32(rowptr[d + 1], (u32)NE);
  float4 acc = make_float4(0.f, 0.f, 0.f, 0.f);
  for (u32 base = start; base < end; base += 32) {
    u32 i = base + l;
    int cnt = (int)umin32(32u, end - base);
    if (i < end) lds_s[g][l] = col[i];
#pragma unroll 4
    for (int j = 0; j < cnt; j++) {
      int s = lds_s[g][j];
      uint2 v = *(const uint2*)(xh + (size_t)s * 64 + l * 2);
      acc.x += lo_f(v.x);
      acc.y += hi_f(v.x);
      acc.z += lo_f(v.y);
      acc.w += hi_f(v.y);
    }
  }
  int c0 = l * 4;
  uint2 sv = *(const uint2*)(xh + (size_t)d * 64 + l * 2);
  float dd = dinv[d];
  float o0 = dd * (acc.x + lo_f(sv.x)) + bias[c0];
  float o1 = dd * (acc.y + hi_f(sv.x)) + bias[c0 + 1];
  float o2 = dd * (acc.z + lo_f(sv.y)) + bias[c0 + 2];
  float o3 = dd * (acc.w + hi_f(sv.y)) + bias[c0 + 3];
  *(uint2*)(outh + (size_t)d * 64 + l * 2) = make_uint2(pk2(o0, o1), pk2(o2, o3));
}

// GAT aggregation + residual + LayerNorm + ReLU. 32 lanes/node, online softmax.
// outf!=null -> fp32 final output; else packed bf16 to outh.
__global__ __launch_bounds__(256) void gat_agg_kernel(
    const u32* __restrict__ xh, const float* a_src4, const float* a_dst4, const int* col,
    const u32* rowptr, const u32* __restrict__ hgcnh, const float* gat_b,
    const float* ln_g, const float* ln_b, u32* __restrict__ outh,
    float* __restrict__ outf, int n) {
  __shared__ u32 lds_s[8][32];
  __shared__ float lds_ee[8][32][4];
  int g = threadIdx.x >> 5;
  int l = threadIdx.x & 31;
  int head4 = l >> 3;
  int d = blockIdx.x * 8 + g;
  if (d >= n) return;
  u32 start = umin32(rowptr[d], (u32)NE), end = umin32(rowptr[d + 1], (u32)NE);
  float4 ad = *(const float4*)(a_dst4 + (size_t)d * 4);
  float4 asl = *(const float4*)(a_src4 + (size_t)d * 4);
  float4 es;
  es.x = lrelu(asl.x + ad.x);
  es.y = lrelu(asl.y + ad.y);
  es.z = lrelu(asl.z + ad.z);
  es.w = lrelu(asl.w + ad.w);
  float4 m = es;
  float4 zp = make_float4(0.f, 0.f, 0.f, 0.f);
  float4 acc = make_float4(0.f, 0.f, 0.f, 0.f);
  for (u32 base = start; base < end; base += 32) {
    u32 i = base + l;
    int cnt = (int)umin32(32u, end - base);
    bool act = i < end;
    float4 lg = make_float4(-1e30f, -1e30f, -1e30f, -1e30f);
    int s = 0;
    if (act) {
      s = col[i];
      float4 a = *(const float4*)(a_src4 + (size_t)s * 4);
      lg.x = lrelu(a.x + ad.x);
      lg.y = lrelu(a.y + ad.y);
      lg.z = lrelu(a.z + ad.z);
      lg.w = lrelu(a.w + ad.w);
    }
    float4 cm = lg;
#pragma unroll
    for (int off = 16; off; off >>= 1) {
      cm.x = fmaxf(cm.x, __shfl_xor(cm.x, off));
      cm.y = fmaxf(cm.y, __shfl_xor(cm.y, off));
      cm.z = fmaxf(cm.z, __shfl_xor(cm.z, off));
      cm.w = fmaxf(cm.w, __shfl_xor(cm.w, off));
    }
    float4 mn;
    mn.x = fmaxf(m.x, cm.x);
    mn.y = fmaxf(m.y, cm.y);
    mn.z = fmaxf(m.z, cm.z);
    mn.w = fmaxf(m.w, cm.w);
    float4 f;
    f.x = __expf(m.x - mn.x);
    f.y = __expf(m.y - mn.y);
    f.z = __expf(m.z - mn.z);
    f.w = __expf(m.w - mn.w);
    m = mn;
    zp.x *= f.x;
    zp.y *= f.y;
    zp.z *= f.z;
    zp.w *= f.w;
    float fsel = (head4 == 0) ? f.x : (head4 == 1) ? f.y : (head4 == 2) ? f.z : f.w;
    acc.x *= fsel;
    acc.y *= fsel;
    acc.z *= fsel;
    acc.w *= fsel;
    if (act) {
      float ex = __expf(lg.x - m.x);
      float ey = __expf(lg.y - m.y);
      float ez = __expf(lg.z - m.z);
      float ew = __expf(lg.w - m.w);
      zp.x += ex;
      zp.y += ey;
      zp.z += ez;
      zp.w += ew;
      lds_s[g][l] = (u32)s;
      *(float4*)&lds_ee[g][l][0] = make_float4(ex, ey, ez, ew);
    }
#pragma unroll 4
    for (int j = 0; j < cnt; j++) {
      u32 sg = lds_s[g][j];
      float w = lds_ee[g][j][head4];
      uint2 v = *(const uint2*)(xh + (size_t)sg * 64 + l * 2);
      acc.x = fmaf(w, lo_f(v.x), acc.x);
      acc.y = fmaf(w, hi_f(v.x), acc.y);
      acc.z = fmaf(w, lo_f(v.y), acc.z);
      acc.w = fmaf(w, hi_f(v.y), acc.w);
    }
  }
  float4 ees;
  ees.x = __expf(es.x - m.x);
  ees.y = __expf(es.y - m.y);
  ees.z = __expf(es.z - m.z);
  ees.w = __expf(es.w - m.w);
#pragma unroll
  for (int off = 16; off; off >>= 1) {
    zp.x += __shfl_xor(zp.x, off);
    zp.y += __shfl_xor(zp.y, off);
    zp.z += __shfl_xor(zp.z, off);
    zp.w += __shfl_xor(zp.w, off);
  }
  zp.x += ees.x;
  zp.y += ees.y;
  zp.z += ees.z;
  zp.w += ees.w;
  float wsel = (head4 == 0) ? ees.x : (head4 == 1) ? ees.y : (head4 == 2) ? ees.z : ees.w;
  float zsel = (head4 == 0) ? zp.x : (head4 == 1) ? zp.y : (head4 == 2) ? zp.z : zp.w;
  int c0 = l * 4;
  uint2 sv = *(const uint2*)(xh + (size_t)d * 64 + l * 2);
  acc.x = fmaf(wsel, lo_f(sv.x), acc.x);
  acc.y = fmaf(wsel, hi_f(sv.x), acc.y);
  acc.z = fmaf(wsel, lo_f(sv.y), acc.z);
  acc.w = fmaf(wsel, hi_f(sv.y), acc.w);
  float rz = 1.0f / zsel;
  uint2 hgv = *(const uint2*)(hgcnh + (size_t)d * 64 + l * 2);
  float t0 = acc.x * rz + gat_b[c0] + lo_f(hgv.x);
  float t1 = acc.y * rz + gat_b[c0 + 1] + hi_f(hgv.x);
  float t2 = acc.z * rz + gat_b[c0 + 2] + lo_f(hgv.y);
  float t3 = acc.w * rz + gat_b[c0 + 3] + hi_f(hgv.y);
  float ssum = t0 + t1 + t2 + t3;
#pragma unroll
  for (int off = 16; off; off >>= 1) ssum += __shfl_xor(ssum, off);
  float mu = ssum * (1.0f / 128.0f);
  float d0 = t0 - mu, d1 = t1 - mu, d2 = t2 - mu, d3 = t3 - mu;
  float vv = d0 * d0 + d1 * d1 + d2 * d2 + d3 * d3;
#pragma unroll
  for (int off = 16; off; off >>= 1) vv += __shfl_xor(vv, off);
  float rstd = rsqrtf(vv * (1.0f / 128.0f) + 1e-5f);
  float o0 = fmaxf(fmaf(d0 * rstd, ln_g[c0], ln_b[c0]), 0.f);
  float o1 = fmaxf(fmaf(d1 * rstd, ln_g[c0 + 1], ln_b[c0 + 1]), 0.f);
  float o2 = fmaxf(fmaf(d2 * rstd, ln_g[c0 + 2], ln_b[c0 + 2]), 0.f);
  float o3 = fmaxf(fmaf(d3 * rstd, ln_g[c0 + 3], ln_b[c0 + 3]), 0.f);
  if (outf) {
    *(float4*)(outf + (size_t)d * 128 + c0) = make_float4(o0, o1, o2, o3);
  } else {
    *(uint2*)(outh + (size_t)d * 64 + l * 2) = make_uint2(pk2(o0, o1), pk2(o2, o3));
  }
}

extern "C" void kernel_launch(void* const* d_in, const int* in_sizes, int n_in,
                              void* d_out, int out_size, void* d_ws, size_t ws_size,
                              hipStream_t stream) {
  const int N = NN, E = NE;
  (void)in_sizes;
  (void)n_in;
  (void)out_size;
  (void)ws_size;

  // ---- workspace layout ----
  char* ws = (char*)d_ws;
  size_t off = 0;
  u32* xwh = (u32*)(ws + off);      off += (size_t)N * 64 * 4;
  u32* hbufh = (u32*)(ws + off);    off += (size_t)N * 64 * 4;
  u32* hgcnh = (u32*)(ws + off);    off += (size_t)N * 64 * 4;
  float* asrc = (float*)(ws + off); off += (size_t)N * 4 * 4;
  float* adst = (float*)(ws + off); off += (size_t)N * 4 * 4;
  float* dinv = (float*)(ws + off); off += (size_t)N * 4;
  u32* counts = (u32*)(ws + off);   off += (size_t)N * 4;
  u32* rowptr = (u32*)(ws + off);   off += (size_t)(N + 1) * 4 + 252;
  u32* rank = (u32*)(ws + off);     off += (size_t)E * 4;
  int* col = (int*)(ws + off);      off += (size_t)E * 4;
  float* pf = (float*)(ws + off);   off += (size_t)PF_TOTAL * 4;
  u32* flag = (u32*)(ws + off);     off += 256;

  // ---- input conversion + CSR build (rank / scan / place, one atomic pass) ----
  const int* edge_index = (const int*)d_in[1];
  detect_kernel<<<1, 64, 0, stream>>>((const u32*)d_in[8], edge_index, flag);
  cvt_params_kernel<<<(PF_TOTAL + 255) / 256, 256, 0, stream>>>(
      d_in[2], d_in[3], d_in[4], d_in[5], d_in[6], d_in[7], d_in[8], d_in[9], pf, flag);
  cvt_x_kernel<<<(N * 64 + 255) / 256, 256, 0, stream>>>(d_in[0], hbufh, N * 64, flag);
  zero1_kernel<<<(N + 255) / 256, 256, 0, stream>>>(counts, N);
  rank_kernel<<<(E + 255) / 256, 256, 0, stream>>>(edge_index, counts, rank, E, N, flag);
  scan_kernel<<<1, 1024, 0, stream>>>(counts, rowptr, dinv, N);
  place_kernel<<<(E + 255) / 256, 256, 0, stream>>>(edge_index, rowptr, rank, col, E, N,
                                                    flag);

  const float* gcn_w = pf + 0;
  const float* gcn_b = pf + 49152;
  const float* gat_w = pf + 49536;
  const float* att_s = pf + 98688;
  const float* att_d = pf + 99072;
  const float* gat_b = pf + 99456;
  const float* ln_g = pf + 99840;
  const float* ln_b = pf + 100224;

  // ---- 3 layers ----
  int gblocks = (N + 127) / 128;
  int ablocks = (N + 7) / 8;
  for (int l = 0; l < 3; l++) {
    gemm_kernel<<<gblocks, 256, 0, stream>>>(hbufh, gcn_w + (size_t)l * 16384, xwh, dinv,
                                             (const float*)0, (const float*)0, (float*)0,
                                             (float*)0, N);
    gcn_agg_kernel<<<ablocks, 256, 0, stream>>>(xwh, col, rowptr, dinv, gcn_b + l * 128,
                                                hgcnh, N);
    gemm_kernel<<<gblocks, 256, 0, stream>>>(hgcnh, gat_w + (size_t)l * 16384, xwh,
                                             (const float*)0, att_s + l * 128,
                                             att_d + l * 128, asrc, adst, N);
    gat_agg_kernel<<<ablocks, 256, 0, stream>>>(
        xwh, asrc, adst, col, rowptr, hgcnh, gat_b + l * 128, ln_g + l * 128,
        ln_b + l * 128, hbufh, (l < 2) ? (float*)0 : (float*)d_out, N);
  }
}